// Round 4
// baseline (1416.023 us; speedup 1.0000x reference)
//
#include <hip/hip_runtime.h>

#define N_NODES 100000
#define N_EDGES 1600000
#define D_IN    128
#define D_OUT   256
#define NB_SCAN ((N_NODES + 255) / 256)   // 391 blocks for node-indexed scans
#define BLK_ROWS 64

// ---------------------------------------------------------------------------
// Detect whether edge_index was materialized as int64 or int32.
// Values are in [0, 100000). If int64 (LE), every odd int32 word is zero.
// ---------------------------------------------------------------------------
__global__ void detect_idx64_kernel(const int* __restrict__ edge32,
                                    int* __restrict__ flag) {
    if (threadIdx.x == 0 && blockIdx.x == 0) {
        int is64 = 1;
        for (int i = 1; i < 32; i += 2) {
            if (edge32[i] != 0) { is64 = 0; break; }
        }
        *flag = is64;
    }
}

__device__ __forceinline__ int load_dst(const void* edge_raw, int is64, int e) {
    if (is64) return (int)((const long long*)edge_raw)[(long long)N_EDGES + e];
    return ((const int*)edge_raw)[N_EDGES + e];
}
__device__ __forceinline__ int load_src(const void* edge_raw, int is64, int e) {
    if (is64) return (int)((const long long*)edge_raw)[e];
    return ((const int*)edge_raw)[e];
}

// ---------------------------------------------------------------------------
// 1) histogram of destinations into counts[]
// ---------------------------------------------------------------------------
__global__ __launch_bounds__(256) void hist_kernel(
        const void* __restrict__ edge_raw, const int* __restrict__ flag,
        int* __restrict__ counts) {
    int e = blockIdx.x * blockDim.x + threadIdx.x;
    if (e >= N_EDGES) return;
    int dst = load_dst(edge_raw, *flag, e);
    if ((unsigned)dst < N_NODES) atomicAdd(&counts[dst], 1);
}

// ---------------------------------------------------------------------------
// 2a) per-256-block sums of counts -> bsum[NB_SCAN]
// ---------------------------------------------------------------------------
__global__ __launch_bounds__(256) void block_sum_kernel(
        const int* __restrict__ counts, int* __restrict__ bsum) {
    __shared__ int lds[256];
    int t = threadIdx.x;
    int i = blockIdx.x * 256 + t;
    lds[t] = (i < N_NODES) ? counts[i] : 0;
    __syncthreads();
    for (int off = 128; off > 0; off >>= 1) {
        if (t < off) lds[t] += lds[t + off];
        __syncthreads();
    }
    if (t == 0) bsum[blockIdx.x] = lds[0];
}

// ---------------------------------------------------------------------------
// 2b) exclusive scan of bsum (391 elems) in one 512-thread block.
// ---------------------------------------------------------------------------
__global__ __launch_bounds__(512) void scan_bsum_kernel(
        int* __restrict__ bsum, int* __restrict__ row_start) {
    __shared__ int lds[512];
    int t = threadIdx.x;
    lds[t] = (t < NB_SCAN) ? bsum[t] : 0;
    __syncthreads();
    for (int off = 1; off < 512; off <<= 1) {
        int u = (t >= off) ? lds[t - off] : 0;
        __syncthreads();
        lds[t] += u;
        __syncthreads();
    }
    int excl = (t == 0) ? 0 : lds[t - 1];
    if (t < NB_SCAN) bsum[t] = excl;
    if (t == 0) row_start[N_NODES] = N_EDGES;
}

// ---------------------------------------------------------------------------
// 2c) per-element exclusive scan: row_start + cursor init
// ---------------------------------------------------------------------------
__global__ __launch_bounds__(256) void scan_counts_kernel(
        int* __restrict__ counts_cursor, const int* __restrict__ bsum,
        int* __restrict__ row_start) {
    __shared__ int lds[256];
    int t = threadIdx.x;
    int i = blockIdx.x * 256 + t;
    int c = (i < N_NODES) ? counts_cursor[i] : 0;
    lds[t] = c;
    __syncthreads();
    for (int off = 1; off < 256; off <<= 1) {
        int u = (t >= off) ? lds[t - off] : 0;
        __syncthreads();
        lds[t] += u;
        __syncthreads();
    }
    int rs = bsum[blockIdx.x] + lds[t] - c;   // exclusive
    if (i < N_NODES) {
        row_start[i] = rs;
        counts_cursor[i] = rs;                // cursor starts at row_start
    }
}

// ---------------------------------------------------------------------------
// 3) fill CSR with packed entries: src (bits 0..19) | dstlocal (bits 20..25).
//    dstlocal = dst & 63 (row tiles are 64-aligned). pos = cursor[dst]++.
// ---------------------------------------------------------------------------
__global__ __launch_bounds__(256) void fill_kernel(
        const void* __restrict__ edge_raw, const int* __restrict__ flag,
        int* __restrict__ cursor, int* __restrict__ csr_pack) {
    int e = blockIdx.x * blockDim.x + threadIdx.x;
    if (e >= N_EDGES) return;
    int is64 = *flag;
    int src = load_src(edge_raw, is64, e);
    int dst = load_dst(edge_raw, is64, e);
    if ((unsigned)dst >= N_NODES || (unsigned)src >= N_NODES) return;
    int pos = atomicAdd(&cursor[dst], 1);
    csr_pack[pos] = src | ((dst & 63) << 20);
}

// ---------------------------------------------------------------------------
// 4) fused gather + GEMM + ReLU. 64 rows x 256 cols per 256-thread block.
//    Gather is EDGE-PARALLEL: the block's CSR segment is split across the 4
//    waves; each edge = one coalesced 512B H-row read (float2/lane) + 2
//    ds_add_f32 into Xs[dstlocal]. No return value -> no inter-edge
//    dependency -> 8 loads in flight per wave. LDS adds hit 64 consecutive
//    dwords (2-way bank alias = free). GEMM: per-thread 16 rows x 4 cols.
// ---------------------------------------------------------------------------
__global__ __launch_bounds__(256) void gather_gemm_relu_kernel(
        const float* __restrict__ H,
        const int* __restrict__ row_start,
        const int* __restrict__ csr_pack,
        const float* __restrict__ Wm,
        float* __restrict__ out) {
    __shared__ float Xs[BLK_ROWS][D_IN];
    __shared__ int idx_lds[4][64];

    const int g    = blockIdx.x * BLK_ROWS;
    const int tid  = threadIdx.x;
    const int wv   = tid >> 6;
    const int lane = tid & 63;

    // ---- init Xs = H rows (zero past N) ----
    {
        const int kidx = tid & 31;
        const int rg   = tid >> 5;
        #pragma unroll
        for (int j = 0; j < 8; ++j) {
            const int r = rg + j * 8;
            const int row = g + r;
            float4 x = make_float4(0.f, 0.f, 0.f, 0.f);
            if (row < N_NODES)
                x = *reinterpret_cast<const float4*>(H + (size_t)row * D_IN + kidx * 4);
            *reinterpret_cast<float4*>(&Xs[r][kidx * 4]) = x;
        }
    }
    __syncthreads();

    // ---- edge-parallel accumulate ----
    {
        const int seg_beg = row_start[g];
        const int rend    = (g + BLK_ROWS < N_NODES) ? (g + BLK_ROWS) : N_NODES;
        const int seg_end = row_start[rend];
        const int len     = seg_end - seg_beg;
        const int clen    = (len + 3) >> 2;
        const int cbeg    = seg_beg + wv * clen;
        int cend          = cbeg + clen;
        if (cend > seg_end) cend = seg_end;

        const int c2 = lane * 2;

        for (int base = cbeg; base < cend; base += 64) {
            int m = cend - base;
            if (m > 64) m = 64;
            if (lane < m) idx_lds[wv][lane] = csr_pack[base + lane];
            int n = 0;
            for (; n + 8 <= m; n += 8) {
                const int e0 = idx_lds[wv][n + 0];
                const int e1 = idx_lds[wv][n + 1];
                const int e2 = idx_lds[wv][n + 2];
                const int e3 = idx_lds[wv][n + 3];
                const int e4 = idx_lds[wv][n + 4];
                const int e5 = idx_lds[wv][n + 5];
                const int e6 = idx_lds[wv][n + 6];
                const int e7 = idx_lds[wv][n + 7];
                const float2 v0 = ((const float2*)(H + (size_t)(e0 & 0xFFFFF) * D_IN))[lane];
                const float2 v1 = ((const float2*)(H + (size_t)(e1 & 0xFFFFF) * D_IN))[lane];
                const float2 v2 = ((const float2*)(H + (size_t)(e2 & 0xFFFFF) * D_IN))[lane];
                const float2 v3 = ((const float2*)(H + (size_t)(e3 & 0xFFFFF) * D_IN))[lane];
                const float2 v4 = ((const float2*)(H + (size_t)(e4 & 0xFFFFF) * D_IN))[lane];
                const float2 v5 = ((const float2*)(H + (size_t)(e5 & 0xFFFFF) * D_IN))[lane];
                const float2 v6 = ((const float2*)(H + (size_t)(e6 & 0xFFFFF) * D_IN))[lane];
                const float2 v7 = ((const float2*)(H + (size_t)(e7 & 0xFFFFF) * D_IN))[lane];
                atomicAdd(&Xs[e0 >> 20][c2], v0.x); atomicAdd(&Xs[e0 >> 20][c2 + 1], v0.y);
                atomicAdd(&Xs[e1 >> 20][c2], v1.x); atomicAdd(&Xs[e1 >> 20][c2 + 1], v1.y);
                atomicAdd(&Xs[e2 >> 20][c2], v2.x); atomicAdd(&Xs[e2 >> 20][c2 + 1], v2.y);
                atomicAdd(&Xs[e3 >> 20][c2], v3.x); atomicAdd(&Xs[e3 >> 20][c2 + 1], v3.y);
                atomicAdd(&Xs[e4 >> 20][c2], v4.x); atomicAdd(&Xs[e4 >> 20][c2 + 1], v4.y);
                atomicAdd(&Xs[e5 >> 20][c2], v5.x); atomicAdd(&Xs[e5 >> 20][c2 + 1], v5.y);
                atomicAdd(&Xs[e6 >> 20][c2], v6.x); atomicAdd(&Xs[e6 >> 20][c2 + 1], v6.y);
                atomicAdd(&Xs[e7 >> 20][c2], v7.x); atomicAdd(&Xs[e7 >> 20][c2 + 1], v7.y);
            }
            for (; n < m; ++n) {
                const int e0 = idx_lds[wv][n];
                const float2 v = ((const float2*)(H + (size_t)(e0 & 0xFFFFF) * D_IN))[lane];
                atomicAdd(&Xs[e0 >> 20][c2], v.x);
                atomicAdd(&Xs[e0 >> 20][c2 + 1], v.y);
            }
        }
    }
    __syncthreads();

    // ---- GEMM + ReLU: ty -> rows ty*16..+15, tx -> cols tx*4..+3 ----
    const int ty = tid >> 6;
    const int tx = tid & 63;

    float accv[16][4];
    #pragma unroll
    for (int r = 0; r < 16; ++r)
        #pragma unroll
        for (int j = 0; j < 4; ++j) accv[r][j] = 0.f;

    const float* Wp = Wm + tx * 4;

    #pragma unroll 2
    for (int k = 0; k < D_IN; k += 4) {
        const float4 w0 = *reinterpret_cast<const float4*>(Wp + (k + 0) * D_OUT);
        const float4 w1 = *reinterpret_cast<const float4*>(Wp + (k + 1) * D_OUT);
        const float4 w2 = *reinterpret_cast<const float4*>(Wp + (k + 2) * D_OUT);
        const float4 w3 = *reinterpret_cast<const float4*>(Wp + (k + 3) * D_OUT);
        #pragma unroll
        for (int r = 0; r < 16; ++r) {
            const float4 x = *reinterpret_cast<const float4*>(&Xs[ty * 16 + r][k]);
            accv[r][0] = fmaf(x.x, w0.x, accv[r][0]);
            accv[r][0] = fmaf(x.y, w1.x, accv[r][0]);
            accv[r][0] = fmaf(x.z, w2.x, accv[r][0]);
            accv[r][0] = fmaf(x.w, w3.x, accv[r][0]);

            accv[r][1] = fmaf(x.x, w0.y, accv[r][1]);
            accv[r][1] = fmaf(x.y, w1.y, accv[r][1]);
            accv[r][1] = fmaf(x.z, w2.y, accv[r][1]);
            accv[r][1] = fmaf(x.w, w3.y, accv[r][1]);

            accv[r][2] = fmaf(x.x, w0.z, accv[r][2]);
            accv[r][2] = fmaf(x.y, w1.z, accv[r][2]);
            accv[r][2] = fmaf(x.z, w2.z, accv[r][2]);
            accv[r][2] = fmaf(x.w, w3.z, accv[r][2]);

            accv[r][3] = fmaf(x.x, w0.w, accv[r][3]);
            accv[r][3] = fmaf(x.y, w1.w, accv[r][3]);
            accv[r][3] = fmaf(x.z, w2.w, accv[r][3]);
            accv[r][3] = fmaf(x.w, w3.w, accv[r][3]);
        }
    }

    #pragma unroll
    for (int r = 0; r < 16; ++r) {
        const int row = g + ty * 16 + r;
        if (row < N_NODES) {
            float4 o;
            o.x = fmaxf(accv[r][0], 0.f);
            o.y = fmaxf(accv[r][1], 0.f);
            o.z = fmaxf(accv[r][2], 0.f);
            o.w = fmaxf(accv[r][3], 0.f);
            *reinterpret_cast<float4*>(out + (size_t)row * D_OUT + tx * 4) = o;
        }
    }
}

extern "C" void kernel_launch(void* const* d_in, const int* in_sizes, int n_in,
                              void* d_out, int out_size, void* d_ws, size_t ws_size,
                              hipStream_t stream) {
    const float* H    = (const float*)d_in[0];
    const void*  edge = d_in[1];
    const float* Wm   = (const float*)d_in[2];
    float* out = (float*)d_out;

    // workspace layout (16B-aligned)
    const size_t off_rs   = 0;                                              // (N+1) ints
    const size_t off_cur  = ((size_t)(N_NODES + 1) * 4 + 15) & ~(size_t)15;
    const size_t off_csr  = off_cur + (size_t)N_NODES * 4;
    const size_t off_bsum = off_csr + (size_t)N_EDGES * 4;
    const size_t off_flag = off_bsum + (((size_t)NB_SCAN * 4 + 15) & ~(size_t)15);

    int* row_start = (int*)((char*)d_ws + off_rs);
    int* cursor    = (int*)((char*)d_ws + off_cur);   // doubles as counts
    int* csr_pack  = (int*)((char*)d_ws + off_csr);
    int* bsum      = (int*)((char*)d_ws + off_bsum);
    int* flag      = (int*)((char*)d_ws + off_flag);

    detect_idx64_kernel<<<1, 64, 0, stream>>>((const int*)edge, flag);

    hipMemsetAsync(cursor, 0, (size_t)N_NODES * 4, stream);

    const int edge_blocks = (N_EDGES + 255) / 256;
    hist_kernel<<<edge_blocks, 256, 0, stream>>>(edge, flag, cursor);
    block_sum_kernel<<<NB_SCAN, 256, 0, stream>>>(cursor, bsum);
    scan_bsum_kernel<<<1, 512, 0, stream>>>(bsum, row_start);
    scan_counts_kernel<<<NB_SCAN, 256, 0, stream>>>(cursor, bsum, row_start);
    fill_kernel<<<edge_blocks, 256, 0, stream>>>(edge, flag, cursor, csr_pack);

    const int gemm_blocks = (N_NODES + BLK_ROWS - 1) / BLK_ROWS;   // 1563
    gather_gemm_relu_kernel<<<gemm_blocks, 256, 0, stream>>>(
        H, row_start, csr_pack, Wm, out);
}

// Round 5
// 429.449 us; speedup vs baseline: 3.2973x; 3.2973x over previous
//
#include <hip/hip_runtime.h>

#define N_NODES 100000
#define N_EDGES 1600000
#define D_IN    128
#define D_OUT   256
#define NB_SCAN ((N_NODES + 255) / 256)   // 391 blocks for node-indexed scans
#define BLK_ROWS 64

// ---------------------------------------------------------------------------
// Detect whether edge_index was materialized as int64 or int32.
// ---------------------------------------------------------------------------
__global__ void detect_idx64_kernel(const int* __restrict__ edge32,
                                    int* __restrict__ flag) {
    if (threadIdx.x == 0 && blockIdx.x == 0) {
        int is64 = 1;
        for (int i = 1; i < 32; i += 2) {
            if (edge32[i] != 0) { is64 = 0; break; }
        }
        *flag = is64;
    }
}

__device__ __forceinline__ int load_dst(const void* edge_raw, int is64, int e) {
    if (is64) return (int)((const long long*)edge_raw)[(long long)N_EDGES + e];
    return ((const int*)edge_raw)[N_EDGES + e];
}
__device__ __forceinline__ int load_src(const void* edge_raw, int is64, int e) {
    if (is64) return (int)((const long long*)edge_raw)[e];
    return ((const int*)edge_raw)[e];
}

// ---------------------------------------------------------------------------
// 1) histogram of destinations
// ---------------------------------------------------------------------------
__global__ __launch_bounds__(256) void hist_kernel(
        const void* __restrict__ edge_raw, const int* __restrict__ flag,
        int* __restrict__ counts) {
    int e = blockIdx.x * blockDim.x + threadIdx.x;
    if (e >= N_EDGES) return;
    int dst = load_dst(edge_raw, *flag, e);
    if ((unsigned)dst < N_NODES) atomicAdd(&counts[dst], 1);
}

// ---------------------------------------------------------------------------
// 2a) per-256-block sums
// ---------------------------------------------------------------------------
__global__ __launch_bounds__(256) void block_sum_kernel(
        const int* __restrict__ counts, int* __restrict__ bsum) {
    __shared__ int lds[256];
    int t = threadIdx.x;
    int i = blockIdx.x * 256 + t;
    lds[t] = (i < N_NODES) ? counts[i] : 0;
    __syncthreads();
    for (int off = 128; off > 0; off >>= 1) {
        if (t < off) lds[t] += lds[t + off];
        __syncthreads();
    }
    if (t == 0) bsum[blockIdx.x] = lds[0];
}

// ---------------------------------------------------------------------------
// 2b) exclusive scan of bsum
// ---------------------------------------------------------------------------
__global__ __launch_bounds__(512) void scan_bsum_kernel(
        int* __restrict__ bsum, int* __restrict__ row_start) {
    __shared__ int lds[512];
    int t = threadIdx.x;
    lds[t] = (t < NB_SCAN) ? bsum[t] : 0;
    __syncthreads();
    for (int off = 1; off < 512; off <<= 1) {
        int u = (t >= off) ? lds[t - off] : 0;
        __syncthreads();
        lds[t] += u;
        __syncthreads();
    }
    int excl = (t == 0) ? 0 : lds[t - 1];
    if (t < NB_SCAN) bsum[t] = excl;
    if (t == 0) row_start[N_NODES] = N_EDGES;
}

// ---------------------------------------------------------------------------
// 2c) per-element exclusive scan: row_start + cursor init
// ---------------------------------------------------------------------------
__global__ __launch_bounds__(256) void scan_counts_kernel(
        int* __restrict__ counts_cursor, const int* __restrict__ bsum,
        int* __restrict__ row_start) {
    __shared__ int lds[256];
    int t = threadIdx.x;
    int i = blockIdx.x * 256 + t;
    int c = (i < N_NODES) ? counts_cursor[i] : 0;
    lds[t] = c;
    __syncthreads();
    for (int off = 1; off < 256; off <<= 1) {
        int u = (t >= off) ? lds[t - off] : 0;
        __syncthreads();
        lds[t] += u;
        __syncthreads();
    }
    int rs = bsum[blockIdx.x] + lds[t] - c;   // exclusive
    if (i < N_NODES) {
        row_start[i] = rs;
        counts_cursor[i] = rs;
    }
}

// ---------------------------------------------------------------------------
// 3) fill CSR packed: src (bits 0..19) | dstlocal (bits 20..25)
// ---------------------------------------------------------------------------
__global__ __launch_bounds__(256) void fill_kernel(
        const void* __restrict__ edge_raw, const int* __restrict__ flag,
        int* __restrict__ cursor, int* __restrict__ csr_pack) {
    int e = blockIdx.x * blockDim.x + threadIdx.x;
    if (e >= N_EDGES) return;
    int is64 = *flag;
    int src = load_src(edge_raw, is64, e);
    int dst = load_dst(edge_raw, is64, e);
    if ((unsigned)dst >= N_NODES || (unsigned)src >= N_NODES) return;
    int pos = atomicAdd(&cursor[dst], 1);
    csr_pack[pos] = src | ((dst & 63) << 20);
}

// ---------------------------------------------------------------------------
// 4) fused gather + GEMM + ReLU. 64 rows x 256 cols per 256-thread block.
//    Gather: edge-parallel over the block's CSR segment (quartered across
//    waves), 8 loads in flight; entries are CSR-grouped by dstlocal, so
//    accumulate runs in a register and flush with ds_add_f32 only on a
//    row-change (wave-uniform branch). ~16x fewer LDS atomics than R3.
// ---------------------------------------------------------------------------
__global__ __launch_bounds__(256) void gather_gemm_relu_kernel(
        const float* __restrict__ H,
        const int* __restrict__ row_start,
        const int* __restrict__ csr_pack,
        const float* __restrict__ Wm,
        float* __restrict__ out) {
    __shared__ float Xs[BLK_ROWS][D_IN];
    __shared__ int idx_lds[4][64];

    const int g    = blockIdx.x * BLK_ROWS;
    const int tid  = threadIdx.x;
    const int wv   = tid >> 6;
    const int lane = tid & 63;

    // ---- init Xs = H rows (zero past N) ----
    {
        const int kidx = tid & 31;
        const int rg   = tid >> 5;
        #pragma unroll
        for (int j = 0; j < 8; ++j) {
            const int r = rg + j * 8;
            const int row = g + r;
            float4 x = make_float4(0.f, 0.f, 0.f, 0.f);
            if (row < N_NODES)
                x = *reinterpret_cast<const float4*>(H + (size_t)row * D_IN + kidx * 4);
            *reinterpret_cast<float4*>(&Xs[r][kidx * 4]) = x;
        }
    }
    __syncthreads();

    // ---- edge-parallel accumulate with run detection ----
    {
        const int seg_beg = row_start[g];
        const int rend    = (g + BLK_ROWS < N_NODES) ? (g + BLK_ROWS) : N_NODES;
        const int seg_end = row_start[rend];
        const int len     = seg_end - seg_beg;
        const int clen    = (len + 3) >> 2;
        const int cbeg    = seg_beg + wv * clen;
        int cend          = cbeg + clen;
        if (cend > seg_end) cend = seg_end;

        const int c2 = lane * 2;
        int   cur = -1;                    // current dstlocal run
        float2 acc = make_float2(0.f, 0.f);

#define PROC(EV, VV)                                                          \
        {                                                                     \
            const int dl = (EV) >> 20;                                        \
            if (dl != cur) {                                                  \
                if (cur >= 0) {                                               \
                    atomicAdd(&Xs[cur][c2],     acc.x);                       \
                    atomicAdd(&Xs[cur][c2 + 1], acc.y);                       \
                }                                                             \
                cur = dl;                                                     \
                acc = (VV);                                                   \
            } else {                                                          \
                acc.x += (VV).x; acc.y += (VV).y;                             \
            }                                                                 \
        }

        for (int base = cbeg; base < cend; base += 64) {
            int m = cend - base;
            if (m > 64) m = 64;
            if (lane < m) idx_lds[wv][lane] = csr_pack[base + lane];
            int n = 0;
            for (; n + 8 <= m; n += 8) {
                const int e0 = idx_lds[wv][n + 0];
                const int e1 = idx_lds[wv][n + 1];
                const int e2 = idx_lds[wv][n + 2];
                const int e3 = idx_lds[wv][n + 3];
                const int e4 = idx_lds[wv][n + 4];
                const int e5 = idx_lds[wv][n + 5];
                const int e6 = idx_lds[wv][n + 6];
                const int e7 = idx_lds[wv][n + 7];
                const float2 v0 = ((const float2*)(H + (size_t)(e0 & 0xFFFFF) * D_IN))[lane];
                const float2 v1 = ((const float2*)(H + (size_t)(e1 & 0xFFFFF) * D_IN))[lane];
                const float2 v2 = ((const float2*)(H + (size_t)(e2 & 0xFFFFF) * D_IN))[lane];
                const float2 v3 = ((const float2*)(H + (size_t)(e3 & 0xFFFFF) * D_IN))[lane];
                const float2 v4 = ((const float2*)(H + (size_t)(e4 & 0xFFFFF) * D_IN))[lane];
                const float2 v5 = ((const float2*)(H + (size_t)(e5 & 0xFFFFF) * D_IN))[lane];
                const float2 v6 = ((const float2*)(H + (size_t)(e6 & 0xFFFFF) * D_IN))[lane];
                const float2 v7 = ((const float2*)(H + (size_t)(e7 & 0xFFFFF) * D_IN))[lane];
                PROC(e0, v0) PROC(e1, v1) PROC(e2, v2) PROC(e3, v3)
                PROC(e4, v4) PROC(e5, v5) PROC(e6, v6) PROC(e7, v7)
            }
            for (; n < m; ++n) {
                const int e0 = idx_lds[wv][n];
                const float2 v = ((const float2*)(H + (size_t)(e0 & 0xFFFFF) * D_IN))[lane];
                PROC(e0, v)
            }
        }
        if (cur >= 0) {
            atomicAdd(&Xs[cur][c2],     acc.x);
            atomicAdd(&Xs[cur][c2 + 1], acc.y);
        }
#undef PROC
    }
    __syncthreads();

    // ---- GEMM + ReLU: ty -> rows ty*16..+15, tx -> cols tx*4..+3 ----
    const int ty = tid >> 6;
    const int tx = tid & 63;

    float accv[16][4];
    #pragma unroll
    for (int r = 0; r < 16; ++r)
        #pragma unroll
        for (int j = 0; j < 4; ++j) accv[r][j] = 0.f;

    const float* Wp = Wm + tx * 4;

    #pragma unroll 2
    for (int k = 0; k < D_IN; k += 4) {
        const float4 w0 = *reinterpret_cast<const float4*>(Wp + (k + 0) * D_OUT);
        const float4 w1 = *reinterpret_cast<const float4*>(Wp + (k + 1) * D_OUT);
        const float4 w2 = *reinterpret_cast<const float4*>(Wp + (k + 2) * D_OUT);
        const float4 w3 = *reinterpret_cast<const float4*>(Wp + (k + 3) * D_OUT);
        #pragma unroll
        for (int r = 0; r < 16; ++r) {
            const float4 x = *reinterpret_cast<const float4*>(&Xs[ty * 16 + r][k]);
            accv[r][0] = fmaf(x.x, w0.x, accv[r][0]);
            accv[r][0] = fmaf(x.y, w1.x, accv[r][0]);
            accv[r][0] = fmaf(x.z, w2.x, accv[r][0]);
            accv[r][0] = fmaf(x.w, w3.x, accv[r][0]);

            accv[r][1] = fmaf(x.x, w0.y, accv[r][1]);
            accv[r][1] = fmaf(x.y, w1.y, accv[r][1]);
            accv[r][1] = fmaf(x.z, w2.y, accv[r][1]);
            accv[r][1] = fmaf(x.w, w3.y, accv[r][1]);

            accv[r][2] = fmaf(x.x, w0.z, accv[r][2]);
            accv[r][2] = fmaf(x.y, w1.z, accv[r][2]);
            accv[r][2] = fmaf(x.z, w2.z, accv[r][2]);
            accv[r][2] = fmaf(x.w, w3.z, accv[r][2]);

            accv[r][3] = fmaf(x.x, w0.w, accv[r][3]);
            accv[r][3] = fmaf(x.y, w1.w, accv[r][3]);
            accv[r][3] = fmaf(x.z, w2.w, accv[r][3]);
            accv[r][3] = fmaf(x.w, w3.w, accv[r][3]);
        }
    }

    #pragma unroll
    for (int r = 0; r < 16; ++r) {
        const int row = g + ty * 16 + r;
        if (row < N_NODES) {
            float4 o;
            o.x = fmaxf(accv[r][0], 0.f);
            o.y = fmaxf(accv[r][1], 0.f);
            o.z = fmaxf(accv[r][2], 0.f);
            o.w = fmaxf(accv[r][3], 0.f);
            *reinterpret_cast<float4*>(out + (size_t)row * D_OUT + tx * 4) = o;
        }
    }
}

extern "C" void kernel_launch(void* const* d_in, const int* in_sizes, int n_in,
                              void* d_out, int out_size, void* d_ws, size_t ws_size,
                              hipStream_t stream) {
    const float* H    = (const float*)d_in[0];
    const void*  edge = d_in[1];
    const float* Wm   = (const float*)d_in[2];
    float* out = (float*)d_out;

    const size_t off_rs   = 0;
    const size_t off_cur  = ((size_t)(N_NODES + 1) * 4 + 15) & ~(size_t)15;
    const size_t off_csr  = off_cur + (size_t)N_NODES * 4;
    const size_t off_bsum = off_csr + (size_t)N_EDGES * 4;
    const size_t off_flag = off_bsum + (((size_t)NB_SCAN * 4 + 15) & ~(size_t)15);

    int* row_start = (int*)((char*)d_ws + off_rs);
    int* cursor    = (int*)((char*)d_ws + off_cur);
    int* csr_pack  = (int*)((char*)d_ws + off_csr);
    int* bsum      = (int*)((char*)d_ws + off_bsum);
    int* flag      = (int*)((char*)d_ws + off_flag);

    detect_idx64_kernel<<<1, 64, 0, stream>>>((const int*)edge, flag);

    hipMemsetAsync(cursor, 0, (size_t)N_NODES * 4, stream);

    const int edge_blocks = (N_EDGES + 255) / 256;
    hist_kernel<<<edge_blocks, 256, 0, stream>>>(edge, flag, cursor);
    block_sum_kernel<<<NB_SCAN, 256, 0, stream>>>(cursor, bsum);
    scan_bsum_kernel<<<1, 512, 0, stream>>>(bsum, row_start);
    scan_counts_kernel<<<NB_SCAN, 256, 0, stream>>>(cursor, bsum, row_start);
    fill_kernel<<<edge_blocks, 256, 0, stream>>>(edge, flag, cursor, csr_pack);

    const int gemm_blocks = (N_NODES + BLK_ROWS - 1) / BLK_ROWS;   // 1563
    gather_gemm_relu_kernel<<<gemm_blocks, 256, 0, stream>>>(
        H, row_start, csr_pack, Wm, out);
}